// Round 5
// baseline (240.721 us; speedup 1.0000x reference)
//
#include <hip/hip_runtime.h>

#define N_NODES 100000
#define D_INF   128
#define D_HID   256
#define K_CL    16
#define N_EDGES 3200000
#define N_PAIRS 3125        // 6250 16-node tiles / 2 per wave-iteration

typedef __attribute__((ext_vector_type(8))) __bf16  bf16x8;
typedef __attribute__((ext_vector_type(8))) unsigned short u16x8;
typedef __attribute__((ext_vector_type(4))) float   f32x4;

__device__ __forceinline__ unsigned short f2bf(float f) {
    unsigned int u = __builtin_bit_cast(unsigned int, f);
    u += 0x7fffu + ((u >> 16) & 1u);          // RNE
    return (unsigned short)(u >> 16);
}
__device__ __forceinline__ float bflo(unsigned int p) {
    return __builtin_bit_cast(float, p << 16);
}
__device__ __forceinline__ float bfhi(unsigned int p) {
    return __builtin_bit_cast(float, p & 0xffff0000u);
}

// ---------------------------------------------------------------------------
// Fused MLP, MFMA 16x16x32 bf16. Block = 4 waves; wave = PAIR of 16-node
// tiles (each B-frag ds_read feeds 2 MFMAs). W1 transposed f32->bf16 into
// LDS per block (no prep kernel, no global W1T roundtrip). Register-shaped:
// one hidden 16-col accumulator pair live at a time; h chunks round-trip
// through per-wave LDS (in-wave DS ordering, no __syncthreads in loop).
// LDS total 79,872 B -> 2 blocks/CU, 8 waves/CU.
// ---------------------------------------------------------------------------
#define W1S 136      // LDS row stride (bf16): b128 frag reads uniform 8/bank
#define CHS 36       // h-chunk row stride (bf16): b16 writes exactly 2/bank

__global__ __launch_bounds__(256, 2) void mlp_kernel(
    const float* __restrict__ x,  const float* __restrict__ W1,
    const float* __restrict__ b1, const float* __restrict__ W2,
    const float* __restrict__ b2, float* __restrict__ C,
    unsigned short* __restrict__ Cb)
{
    __shared__ unsigned short w1s[256 * W1S];          // 69,632 B
    __shared__ unsigned short chbuf[4][2][16 * CHS];   //  9,216 B
    __shared__ float b1s[D_HID];                       //  1,024 B -> 79,872

    const int tid  = threadIdx.x;
    const int wv   = tid >> 6;
    const int lane = tid & 63;
    const int c    = lane & 15;
    const int q    = lane >> 4;

    // ---- stage W1^T bf16 into LDS: w1s[n][k] = bf16(W1[k][n]) ----
    #pragma unroll
    for (int it = 0; it < 32; ++it) {
        const int idx4 = it * 256 + tid;          // 8192 float4 chunks
        const int k = idx4 >> 6, n4 = (idx4 & 63) * 4;
        const float4 v = ((const float4*)W1)[idx4];
        w1s[(n4 + 0) * W1S + k] = f2bf(v.x);
        w1s[(n4 + 1) * W1S + k] = f2bf(v.y);
        w1s[(n4 + 2) * W1S + k] = f2bf(v.z);
        w1s[(n4 + 3) * W1S + k] = f2bf(v.w);
    }
    if (tid < D_HID) b1s[tid] = b1[tid];

    // ---- W2 fragments direct from f32 (16 KB, L2-resident), 32 VGPRs ----
    bf16x8 w2f[8];
    #pragma unroll
    for (int kc2 = 0; kc2 < 8; ++kc2) {
        u16x8 t;
        #pragma unroll
        for (int j = 0; j < 8; ++j)
            t[j] = f2bf(W2[(kc2 * 32 + q * 8 + j) * K_CL + c]);
        w2f[kc2] = __builtin_bit_cast(bf16x8, t);
    }
    const float b2v = b2[c];
    __syncthreads();

    unsigned short* const cb0 = &chbuf[wv][0][0];
    unsigned short* const cb1 = &chbuf[wv][1][0];

    const int wid     = blockIdx.x * 4 + wv;
    const int wstride = gridDim.x * 4;

    for (int pair = wid; pair < N_PAIRS; pair += wstride) {
        const int m0 = pair * 32;

        // ---- A fragments for both tiles (32 VGPRs), x fp32 -> bf16 ----
        const float* xr0 = x + (size_t)(m0 + c) * D_INF + q * 8;
        const float* xr1 = xr0 + 16 * D_INF;
        bf16x8 af0[4], af1[4];
        #pragma unroll
        for (int kc = 0; kc < 4; ++kc) {
            float4 a = *(const float4*)(xr0 + kc * 32);
            float4 b = *(const float4*)(xr0 + kc * 32 + 4);
            u16x8 t;
            t[0] = f2bf(a.x); t[1] = f2bf(a.y); t[2] = f2bf(a.z); t[3] = f2bf(a.w);
            t[4] = f2bf(b.x); t[5] = f2bf(b.y); t[6] = f2bf(b.z); t[7] = f2bf(b.w);
            af0[kc] = __builtin_bit_cast(bf16x8, t);
            a = *(const float4*)(xr1 + kc * 32);
            b = *(const float4*)(xr1 + kc * 32 + 4);
            t[0] = f2bf(a.x); t[1] = f2bf(a.y); t[2] = f2bf(a.z); t[3] = f2bf(a.w);
            t[4] = f2bf(b.x); t[5] = f2bf(b.y); t[6] = f2bf(b.z); t[7] = f2bf(b.w);
            af1[kc] = __builtin_bit_cast(bf16x8, t);
        }

        // ---- fused GEMM1 -> h chunks -> GEMM2 ----
        f32x4 acc2_0 = (f32x4){0.f, 0.f, 0.f, 0.f};
        f32x4 acc2_1 = (f32x4){0.f, 0.f, 0.f, 0.f};
        #pragma unroll
        for (int kc2 = 0; kc2 < 8; ++kc2) {
            #pragma unroll
            for (int half = 0; half < 2; ++half) {
                const int nt = kc2 * 2 + half;
                f32x4 p0 = (f32x4){0.f, 0.f, 0.f, 0.f};
                f32x4 p1 = (f32x4){0.f, 0.f, 0.f, 0.f};
                #pragma unroll
                for (int kc = 0; kc < 4; ++kc) {
                    const bf16x8 bf =
                        *(const bf16x8*)&w1s[(nt * 16 + c) * W1S + kc * 32 + q * 8];
                    p0 = __builtin_amdgcn_mfma_f32_16x16x32_bf16(af0[kc], bf, p0, 0, 0, 0);
                    p1 = __builtin_amdgcn_mfma_f32_16x16x32_bf16(af1[kc], bf, p1, 0, 0, 0);
                }
                const float bv = b1s[nt * 16 + c];
                #pragma unroll
                for (int r = 0; r < 4; ++r) {
                    cb0[(4 * q + r) * CHS + half * 16 + c] = f2bf(fmaxf(p0[r] + bv, 0.f));
                    cb1[(4 * q + r) * CHS + half * 16 + c] = f2bf(fmaxf(p1[r] + bv, 0.f));
                }
            }
            const bf16x8 a20 = *(const bf16x8*)&cb0[c * CHS + q * 8];
            const bf16x8 a21 = *(const bf16x8*)&cb1[c * CHS + q * 8];
            acc2_0 = __builtin_amdgcn_mfma_f32_16x16x32_bf16(a20, w2f[kc2], acc2_0, 0, 0, 0);
            acc2_1 = __builtin_amdgcn_mfma_f32_16x16x32_bf16(a21, w2f[kc2], acc2_1, 0, 0, 0);
        }

        // ---- softmax (rows m = 4q+r, across 16 c-lanes) + dual store ----
        #pragma unroll
        for (int t2 = 0; t2 < 2; ++t2) {
            const f32x4 a2 = t2 ? acc2_1 : acc2_0;
            const int mb = m0 + t2 * 16;
            #pragma unroll
            for (int r = 0; r < 4; ++r) {
                const float l = a2[r] + b2v;
                float mx = l;
                mx = fmaxf(mx, __shfl_xor(mx, 1));
                mx = fmaxf(mx, __shfl_xor(mx, 2));
                mx = fmaxf(mx, __shfl_xor(mx, 4));
                mx = fmaxf(mx, __shfl_xor(mx, 8));
                const float e = __expf(l - mx);
                float sm = e;
                sm += __shfl_xor(sm, 1);
                sm += __shfl_xor(sm, 2);
                sm += __shfl_xor(sm, 4);
                sm += __shfl_xor(sm, 8);
                const float p = e / sm;
                const size_t o = (size_t)(mb + 4 * q + r) * K_CL + c;
                C[o]  = p;
                Cb[o] = f2bf(p);
            }
        }
    }
}

// ---------------------------------------------------------------------------
// Edge reduction v3: one-shot, 128 edges per wave, no loop. Coalesced idx
// loads -> shfl broadcast -> 2 lanes/edge uint4 gathers from bf16 C copy
// (3.2 MB, L2-resident). 12 VMEM instr / 128 edges.
// ---------------------------------------------------------------------------
__global__ __launch_bounds__(256) void edge_kernel(
    const int* __restrict__ ei, const unsigned short* __restrict__ Cb,
    float* __restrict__ acc)
{
    __shared__ float red[4];
    const int tid  = threadIdx.x;
    const int lane = tid & 63;
    const int wv   = tid >> 6;
    const int base = (blockIdx.x * 4 + wv) * 128;

    const int u0 = ei[base + lane];
    const int u1 = ei[base + 64 + lane];
    const int v0 = ei[N_EDGES + base + lane];
    const int v1 = ei[N_EDGES + base + 64 + lane];

    const int half8 = (lane & 1) * 8;    // which 16 B of the 32 B row
    const int sl    = lane >> 1;

    float s = 0.f;
    #pragma unroll
    for (int g = 0; g < 4; ++g) {
        const int src = (g & 1) * 32 + sl;
        const int ue  = __shfl((g < 2) ? u0 : u1, src);
        const int ve  = __shfl((g < 2) ? v0 : v1, src);
        const uint4 a = *(const uint4*)(Cb + (size_t)ue * K_CL + half8);
        const uint4 b = *(const uint4*)(Cb + (size_t)ve * K_CL + half8);
        s = fmaf(bflo(a.x), bflo(b.x), s);
        s = fmaf(bfhi(a.x), bfhi(b.x), s);
        s = fmaf(bflo(a.y), bflo(b.y), s);
        s = fmaf(bfhi(a.y), bfhi(b.y), s);
        s = fmaf(bflo(a.z), bflo(b.z), s);
        s = fmaf(bfhi(a.z), bfhi(b.z), s);
        s = fmaf(bflo(a.w), bflo(b.w), s);
        s = fmaf(bfhi(a.w), bfhi(b.w), s);
    }
    s += __shfl_xor(s, 1);
    s += __shfl_xor(s, 2);
    s += __shfl_xor(s, 4);
    s += __shfl_xor(s, 8);
    s += __shfl_xor(s, 16);
    s += __shfl_xor(s, 32);
    if (lane == 0) red[wv] = s;
    __syncthreads();
    if (tid == 0) atomicAdd(acc, red[0] + red[1] + red[2] + red[3]);
}

__global__ void finalize_kernel(const float* __restrict__ acc,
                                float* __restrict__ out)
{
    out[(size_t)N_NODES * K_CL] = -acc[0] / (float)N_EDGES;
}

// ---------------------------------------------------------------------------
extern "C" void kernel_launch(void* const* d_in, const int* in_sizes, int n_in,
                              void* d_out, int out_size, void* d_ws, size_t ws_size,
                              hipStream_t stream) {
    const float* x  = (const float*)d_in[0];
    const int*   ei = (const int*)  d_in[1];
    const float* W1 = (const float*)d_in[2];
    const float* b1 = (const float*)d_in[3];
    const float* W2 = (const float*)d_in[4];
    const float* b2 = (const float*)d_in[5];
    float* out = (float*)d_out;

    // ws: acc f32 @0, Cb bf16 [100000*16] @64 (3.2 MB)
    float*          acc = (float*)d_ws;
    unsigned short* Cb  = (unsigned short*)((char*)d_ws + 64);

    hipMemsetAsync(d_ws, 0, sizeof(float), stream);
    mlp_kernel<<<512, 256, 0, stream>>>(x, W1, b1, W2, b2, out, Cb);
    edge_kernel<<<N_EDGES / 512, 256, 0, stream>>>(ei, Cb, acc);  // 6250
    finalize_kernel<<<1, 1, 0, stream>>>(acc, out);
}

// Round 6
// 155.238 us; speedup vs baseline: 1.5507x; 1.5507x over previous
//
#include <hip/hip_runtime.h>

#define N_NODES 100000
#define D_INF   128
#define D_HID   256
#define K_CL    16
#define N_EDGES 3200000
#define N_TILES (N_NODES / 16)      // 6250, exact
#define EDGE_BLOCKS (N_EDGES / 512) // 6250: 4 waves x 128 edges each

typedef __attribute__((ext_vector_type(8))) __bf16  bf16x8;
typedef __attribute__((ext_vector_type(8))) unsigned short u16x8;
typedef __attribute__((ext_vector_type(4))) float   f32x4;

__device__ __forceinline__ unsigned short f2bf(float f) {
    unsigned int u = __builtin_bit_cast(unsigned int, f);
    u += 0x7fffu + ((u >> 16) & 1u);          // RNE
    return (unsigned short)(u >> 16);
}
__device__ __forceinline__ float bflo(unsigned int p) {
    return __builtin_bit_cast(float, p << 16);
}
__device__ __forceinline__ float bfhi(unsigned int p) {
    return __builtin_bit_cast(float, p & 0xffff0000u);
}

// ---------------------------------------------------------------------------
// Prep: W1 [128][256] f32 -> W1T [256][128] bf16 ; W2 [256][16] f32 -> W2T
// [16][256] bf16. Writes coalesced (reads are small/L2-resident).
// ---------------------------------------------------------------------------
__global__ void prep_kernel(const float* __restrict__ W1,
                            const float* __restrict__ W2,
                            unsigned short* __restrict__ w1t,
                            unsigned short* __restrict__ w2t)
{
    const int i = blockIdx.x * 256 + threadIdx.x;
    if (i < D_INF * D_HID) {                  // w1t[n][k] = W1[k][n]
        const int n = i >> 7, k = i & 127;
        w1t[i] = f2bf(W1[k * D_HID + n]);
    }
    if (i < D_HID * K_CL) {                   // w2t[t][n] = W2[n][t]
        const int t = i >> 8, n = i & 255;
        w2t[i] = f2bf(W2[n * K_CL + t]);
    }
}

// ---------------------------------------------------------------------------
// Fused MLP (R4 known-good). MFMA 16x16x32 bf16. Block = 4 waves; wave = one
// 16-node tile, grid-stride over 6250 tiles. W1T staged in LDS per block.
// Register-pressure-shaped K-loop: one hidden 16-col accumulator live at a
// time; h chunk round-trips through per-wave LDS (in-wave DS ordering,
// no __syncthreads in the loop).
// ---------------------------------------------------------------------------
#define W1S 136      // LDS row stride (bf16) for W1T
#define CHS 40       // LDS row stride (bf16) for h chunk

__global__ __launch_bounds__(256, 2) void mlp_kernel(
    const float* __restrict__ x, const unsigned short* __restrict__ W1T,
    const float* __restrict__ b1, const unsigned short* __restrict__ W2T,
    const float* __restrict__ b2, float* __restrict__ C,
    unsigned short* __restrict__ Cb)
{
    __shared__ unsigned short w1s[256 * W1S];          // 69,632 B
    __shared__ unsigned short chbuf[4][2][16 * CHS];   // 10,240 B
    __shared__ float b1s[D_HID];                       //  1,024 B -> 80,896

    const int tid  = threadIdx.x;
    const int wv   = tid >> 6;
    const int lane = tid & 63;
    const int c    = lane & 15;
    const int q    = lane >> 4;

    // ---- stage W1T into LDS (coalesced uint4 reads, b128 LDS writes) ----
    #pragma unroll
    for (int it = 0; it < 16; ++it) {
        const int idx = it * 256 + tid;        // 4096 uint4 chunks
        const int row = idx >> 4, ch = idx & 15;
        const uint4 v = ((const uint4*)W1T)[idx];
        *(uint4*)&w1s[row * W1S + ch * 8] = v;
    }
    if (tid < D_HID) b1s[tid] = b1[tid];

    // ---- loop-invariant registers: W2T fragments (32 VGPRs), b2 ----
    bf16x8 w2f[8];
    #pragma unroll
    for (int kc2 = 0; kc2 < 8; ++kc2)
        w2f[kc2] = *(const bf16x8*)(W2T + (size_t)c * D_HID + kc2 * 32 + q * 8);
    const float b2v = b2[c];
    __syncthreads();

    unsigned short* const chA = &chbuf[wv][0][0];
    unsigned short* const chB = &chbuf[wv][1][0];

    const int wid     = blockIdx.x * 4 + wv;
    const int wstride = gridDim.x * 4;

    for (int tile = wid; tile < N_TILES; tile += wstride) {
        const int m0 = tile * 16;

        // ---- A fragments: x row m0+c, fp32 -> bf16 in regs (16 VGPRs) ----
        const float* xrow = x + (size_t)(m0 + c) * D_INF + q * 8;
        bf16x8 afr[4];
        #pragma unroll
        for (int kc = 0; kc < 4; ++kc) {
            const float4 xa = *(const float4*)(xrow + kc * 32);
            const float4 xb = *(const float4*)(xrow + kc * 32 + 4);
            u16x8 af;
            af[0] = f2bf(xa.x); af[1] = f2bf(xa.y); af[2] = f2bf(xa.z); af[3] = f2bf(xa.w);
            af[4] = f2bf(xb.x); af[5] = f2bf(xb.y); af[6] = f2bf(xb.z); af[7] = f2bf(xb.w);
            afr[kc] = __builtin_bit_cast(bf16x8, af);
        }

        // ---- fused GEMM1 -> h chunk -> GEMM2, one nt-pair at a time ----
        f32x4 acc2 = (f32x4){0.f, 0.f, 0.f, 0.f};
        #pragma unroll
        for (int kc2 = 0; kc2 < 8; ++kc2) {
            unsigned short* const cb = (kc2 & 1) ? chB : chA;
            #pragma unroll
            for (int half = 0; half < 2; ++half) {
                const int nt = kc2 * 2 + half;
                f32x4 a1 = (f32x4){0.f, 0.f, 0.f, 0.f};
                #pragma unroll
                for (int kc = 0; kc < 4; ++kc) {
                    const bf16x8 bf =
                        *(const bf16x8*)&w1s[(nt * 16 + c) * W1S + kc * 32 + q * 8];
                    a1 = __builtin_amdgcn_mfma_f32_16x16x32_bf16(afr[kc], bf, a1, 0, 0, 0);
                }
                const float bv = b1s[nt * 16 + c];
                #pragma unroll
                for (int r = 0; r < 4; ++r)
                    cb[(4 * q + r) * CHS + half * 16 + c] =
                        f2bf(fmaxf(a1[r] + bv, 0.f));
            }
            const bf16x8 a2 = *(const bf16x8*)&cb[c * CHS + q * 8];
            acc2 = __builtin_amdgcn_mfma_f32_16x16x32_bf16(a2, w2f[kc2], acc2, 0, 0, 0);
        }

        // ---- softmax per row m = 4q+r across 16 c-lanes; dual store ----
        #pragma unroll
        for (int r = 0; r < 4; ++r) {
            const float l = acc2[r] + b2v;
            float mx = l;
            mx = fmaxf(mx, __shfl_xor(mx, 1));
            mx = fmaxf(mx, __shfl_xor(mx, 2));
            mx = fmaxf(mx, __shfl_xor(mx, 4));
            mx = fmaxf(mx, __shfl_xor(mx, 8));
            const float e = __expf(l - mx);
            float sm = e;
            sm += __shfl_xor(sm, 1);
            sm += __shfl_xor(sm, 2);
            sm += __shfl_xor(sm, 4);
            sm += __shfl_xor(sm, 8);
            const float p = e / sm;
            const size_t o = (size_t)(m0 + 4 * q + r) * K_CL + c;
            C[o]  = p;
            Cb[o] = f2bf(p);
        }
    }
}

// ---------------------------------------------------------------------------
// Edge reduction: one-shot, 128 edges per wave. Coalesced idx loads -> shfl
// broadcast -> 2 lanes/edge uint4 gathers from bf16 C copy (3.2 MB, L2).
// NO ATOMICS: block partial -> partials[blockIdx] (plain store).
// ---------------------------------------------------------------------------
__global__ __launch_bounds__(256) void edge_kernel(
    const int* __restrict__ ei, const unsigned short* __restrict__ Cb,
    float* __restrict__ partials)
{
    __shared__ float red[4];
    const int tid  = threadIdx.x;
    const int lane = tid & 63;
    const int wv   = tid >> 6;
    const int base = (blockIdx.x * 4 + wv) * 128;

    const int u0 = ei[base + lane];
    const int u1 = ei[base + 64 + lane];
    const int v0 = ei[N_EDGES + base + lane];
    const int v1 = ei[N_EDGES + base + 64 + lane];

    const int half8 = (lane & 1) * 8;    // which 16 B of the 32 B row
    const int sl    = lane >> 1;

    float s = 0.f;
    #pragma unroll
    for (int g = 0; g < 4; ++g) {
        const int src = (g & 1) * 32 + sl;
        const int ue  = __shfl((g < 2) ? u0 : u1, src);
        const int ve  = __shfl((g < 2) ? v0 : v1, src);
        const uint4 a = *(const uint4*)(Cb + (size_t)ue * K_CL + half8);
        const uint4 b = *(const uint4*)(Cb + (size_t)ve * K_CL + half8);
        s = fmaf(bflo(a.x), bflo(b.x), s);
        s = fmaf(bfhi(a.x), bfhi(b.x), s);
        s = fmaf(bflo(a.y), bflo(b.y), s);
        s = fmaf(bfhi(a.y), bfhi(b.y), s);
        s = fmaf(bflo(a.z), bflo(b.z), s);
        s = fmaf(bfhi(a.z), bfhi(b.z), s);
        s = fmaf(bflo(a.w), bflo(b.w), s);
        s = fmaf(bfhi(a.w), bfhi(b.w), s);
    }
    s += __shfl_xor(s, 1);
    s += __shfl_xor(s, 2);
    s += __shfl_xor(s, 4);
    s += __shfl_xor(s, 8);
    s += __shfl_xor(s, 16);
    s += __shfl_xor(s, 32);
    if (lane == 0) red[wv] = s;
    __syncthreads();
    if (tid == 0) partials[blockIdx.x] = red[0] + red[1] + red[2] + red[3];
}

// ---------------------------------------------------------------------------
// Finalize: reduce 6250 block partials, write -sum/E. One 256-thread block.
// ---------------------------------------------------------------------------
__global__ __launch_bounds__(256) void finalize_kernel(
    const float* __restrict__ partials, float* __restrict__ out)
{
    __shared__ float red[4];
    const int tid = threadIdx.x;
    float s = 0.f;
    for (int i = tid; i < EDGE_BLOCKS; i += 256) s += partials[i];
    s += __shfl_xor(s, 1);
    s += __shfl_xor(s, 2);
    s += __shfl_xor(s, 4);
    s += __shfl_xor(s, 8);
    s += __shfl_xor(s, 16);
    s += __shfl_xor(s, 32);
    if ((tid & 63) == 0) red[tid >> 6] = s;
    __syncthreads();
    if (tid == 0)
        out[(size_t)N_NODES * K_CL] =
            -(red[0] + red[1] + red[2] + red[3]) / (float)N_EDGES;
}

// ---------------------------------------------------------------------------
extern "C" void kernel_launch(void* const* d_in, const int* in_sizes, int n_in,
                              void* d_out, int out_size, void* d_ws, size_t ws_size,
                              hipStream_t stream) {
    const float* x  = (const float*)d_in[0];
    const int*   ei = (const int*)  d_in[1];
    const float* W1 = (const float*)d_in[2];
    const float* b1 = (const float*)d_in[3];
    const float* W2 = (const float*)d_in[4];
    const float* b2 = (const float*)d_in[5];
    float* out = (float*)d_out;

    // ws: W1T bf16 @0 (64 KB), W2T bf16 @65536 (8 KB),
    //     Cb bf16 [100000*16] @73760 (3.2 MB), partials f32 @3273760 (25 KB)
    unsigned short* w1t      = (unsigned short*)d_ws;
    unsigned short* w2t      = (unsigned short*)((char*)d_ws + 65536);
    unsigned short* Cb       = (unsigned short*)((char*)d_ws + 73760);
    float*          partials = (float*)((char*)d_ws + 3273760);

    prep_kernel<<<128, 256, 0, stream>>>(W1, W2, w1t, w2t);
    mlp_kernel<<<512, 256, 0, stream>>>(x, w1t, b1, w2t, b2, out, Cb);
    edge_kernel<<<EDGE_BLOCKS, 256, 0, stream>>>(ei, Cb, partials);
    finalize_kernel<<<1, 256, 0, stream>>>(partials, out);
}